// Round 7
// baseline (2541.717 us; speedup 1.0000x reference)
//
#include <hip/hip_runtime.h>
#include <stdint.h>

#define BB 4
#define NN 16384
#define NPOINT 1024
#define NSAMPLE 32
#define CC 64
#define RADIUS2 0.00999999977648258209228515625f
#define BIGF 1.0e10f

#define FT 1024    // fps threads per block (16 waves, one CU per batch)
#define NPAIR 8    // point-pairs per thread (16 points/thread)

typedef float f32x2 __attribute__((ext_vector_type(2)));

// ---------------- repack w1 (64x67) -> (64x68) padded, pad=0 ----------------
__global__ __launch_bounds__(256) void repack_w1(const float* __restrict__ w1,
                                                 float* __restrict__ w1p) {
    int t = threadIdx.x;
    for (int i = t; i < 64 * 68; i += 256) {
        int o = i / 68, c = i % 68;
        w1p[i] = (c < 67) ? w1[o * 67 + c] : 0.0f;
    }
}

// DPP-based argmax step (max value, min index on ties) — validated bit-exact.
template <int CTRL>
__device__ __forceinline__ void amax_step(float& v, int& i) {
    int nv = __builtin_amdgcn_update_dpp(__float_as_int(v), __float_as_int(v),
                                         CTRL, 0xf, 0xf, false);
    int ni = __builtin_amdgcn_update_dpp(i, i, CTRL, 0xf, 0xf, false);
    float fv = __int_as_float(nv);
    if (fv > v || (fv == v && ni < i)) { v = fv; i = ni; }
}
__device__ __forceinline__ void wave_amax(float& v, int& i) {
    amax_step<0x111>(v, i);  // row_shr:1
    amax_step<0x112>(v, i);  // row_shr:2
    amax_step<0x114>(v, i);  // row_shr:4
    amax_step<0x118>(v, i);  // row_shr:8
    amax_step<0x142>(v, i);  // row_bcast:15
    amax_step<0x143>(v, i);  // row_bcast:31  -> lane63 holds full wave result
}

// ---------------- FPS: one 1024-thread block per batch ----------------
// R0-R6 ledger: single-CU variants (regs / anchored / LDS) all 2.1-2.35us/iter
// at 71-85% ACTIVE-CU VALUBusy; multi-CU variants (R1, R6) 2.16-2.27us/iter
// bound by a ~1.7-1.8us cross-CU exchange round trip (closed arm).
// The single-CU counters imply ~550 wave-instr/iter issued vs ~150 written:
// ~3.5x bloat. Suspect: the hand-written v_pk_* inline asm -- every asm op
// requires aligned VGPR pairs, and with ~24 live pairs the allocator emits
// v_mov shuffles around nearly every asm (catalog m240: hand-packed asm is
// -37% vs scalar; the compiler packs fine on its own).
// R7 = R4 structure unchanged (LDS x/y planes, reg z+dd, LDS centroid stash,
// batched ds_read_b64, validated DPP reduce) with ALL pk asm replaced by
// plain scalar __fsub_rn/__fmul_rn/__fadd_rn/fminf. Bit-exact: pk_add(p,-c)
// was elementwise p+(-c) == __fsub_rn(p,c); products/sums individually
// rounded in the same order; same ascending argmax scan.
__global__ __launch_bounds__(FT)
void fps_kernel(const float* xyz, float* new_xyz) {
    const int b = blockIdx.x;
    const int t = threadIdx.x;
    const int lane = t & 63;
    const int w = t >> 6;  // 0..15

    __shared__ float sx[NN];          // 64 KB
    __shared__ float sy[NN];          // 64 KB
    __shared__ float st[3 * NPOINT];  // 12 KB centroid stash
    __shared__ float2 svi[2][16];     // parity double-buffered (v, idx)

    const float* xb = xyz + (size_t)b * NN * 3;

    f32x2 pz[NPAIR];
    f32x2 dd[NPAIR];

    // load + transpose: pair k covers points g = 2*(k*FT+t) and g+1
#pragma unroll
    for (int k = 0; k < NPAIR; ++k) {
        const float* p = xb + (size_t)6 * (k * FT + t);
        f32x2 a = *(const f32x2*)(p + 0);
        f32x2 bq = *(const f32x2*)(p + 2);
        f32x2 c = *(const f32x2*)(p + 4);
        int g = 2 * (k * FT + t);
        f32x2 vx; vx.x = a.x; vx.y = bq.y;
        f32x2 vy; vy.x = a.y; vy.y = c.x;
        *(f32x2*)&sx[g] = vx;      // ds_write_b64, 2-way bank alias (free)
        *(f32x2*)&sy[g] = vy;
        pz[k].x = bq.x; pz[k].y = c.y;
        dd[k].x = BIGF; dd[k].y = BIGF;
    }
    // one-time remat-blocker: pz is now defined by the asm, not by a load.
#pragma unroll
    for (int k = 0; k < NPAIR; ++k) asm("" : "+v"(pz[k]));

    // initial centroid = point 0
    float cx = xb[0], cy = xb[1], cz = xb[2];
    __syncthreads();

    for (int i = 0; i < NPOINT; ++i) {
        if (t == 0) {  // stash centroid in LDS; dumped to global after loop
            st[3 * i + 0] = cx; st[3 * i + 1] = cy; st[3 * i + 2] = cz;
        }
        if (i == NPOINT - 1) break;  // last centroid stashed; no next needed

        // ---- load phase: all 16 ds_read_b64 in flight together ----
        f32x2 vx[NPAIR], vy[NPAIR];
#pragma unroll
        for (int k = 0; k < NPAIR; ++k) {
            vx[k] = *(const f32x2*)&sx[2 * (k * FT + t)];
            vy[k] = *(const f32x2*)&sy[2 * (k * FT + t)];
        }

        // ---- compute phase: plain scalar math (compiler schedules/packs) ----
        float bv = -1.0f;
        int bj = 0;
        // EXACT numpy semantics per element: sub; products rounded
        // individually; sum order (x^2+y^2)+z^2; min; running max with strict
        // > and ascending local slot -> first-occurrence tie-break.
#pragma unroll
        for (int k = 0; k < NPAIR; ++k) {
            float dx0 = __fsub_rn(vx[k].x, cx);
            float dy0 = __fsub_rn(vy[k].x, cy);
            float dz0 = __fsub_rn(pz[k].x, cz);
            float d0 = __fadd_rn(__fadd_rn(__fmul_rn(dx0, dx0),
                                           __fmul_rn(dy0, dy0)),
                                 __fmul_rn(dz0, dz0));
            float dx1 = __fsub_rn(vx[k].y, cx);
            float dy1 = __fsub_rn(vy[k].y, cy);
            float dz1 = __fsub_rn(pz[k].y, cz);
            float d1 = __fadd_rn(__fadd_rn(__fmul_rn(dx1, dx1),
                                           __fmul_rn(dy1, dy1)),
                                 __fmul_rn(dz1, dz1));
            dd[k].x = fminf(dd[k].x, d0);
            dd[k].y = fminf(dd[k].y, d1);
            if (dd[k].x > bv) { bv = dd[k].x; bj = 2 * k; }
            if (dd[k].y > bv) { bv = dd[k].y; bj = 2 * k + 1; }
        }
        // global index: g = (bj>>1)*2*FT + 2*t + (bj&1); monotone in bj for
        // fixed t -> in-thread first-occurrence holds
        int bi = (bj >> 1) * (2 * FT) + 2 * t + (bj & 1);

        wave_amax(bv, bi);
        if (lane == 63) svi[i & 1][w] = make_float2(bv, __int_as_float(bi));
        __syncthreads();

        // each lane reads ONE of the 16 wave slots; lanes 48..63 cover slots
        // 0..15, so 4 row_shr steps make lane63 the full block reduction.
        float2 s = svi[i & 1][lane & 15];
        float v2 = s.x;
        int i2 = __float_as_int(s.y);
        amax_step<0x111>(v2, i2);  // row_shr:1
        amax_step<0x112>(v2, i2);  // row_shr:2
        amax_step<0x114>(v2, i2);  // row_shr:4
        amax_step<0x118>(v2, i2);  // row_shr:8
        int ixs = __builtin_amdgcn_readlane(i2, 63);  // uniform -> SGPR

        // next centroid: x,y from LDS (exact copies), z via scalar load
        cx = sx[ixs];
        cy = sy[ixs];
        cz = xb[ixs * 3 + 2];
    }

    // dump stash -> global, coalesced (3 stores/thread)
    __syncthreads();
    float* ob = new_xyz + (size_t)b * NPOINT * 3;
#pragma unroll
    for (int j = 0; j < 3; ++j) ob[j * FT + t] = st[j * FT + t];
}

// ---------------- ball query: one wave per centroid ----------------
__global__ __launch_bounds__(256) void ballquery_kernel(const float* __restrict__ xyz,
                                                        const float* __restrict__ new_xyz,
                                                        int* __restrict__ nidx) {
    const int t = threadIdx.x;
    const int lane = t & 63;
    const int w = t >> 6;
    const int cid = blockIdx.x * 4 + w;  // 0..4095
    const int b = cid >> 10;

    __shared__ int list[4][NSAMPLE];

    const float* xb = xyz + (size_t)b * NN * 3;
    const float* c = new_xyz + (size_t)cid * 3;
    float cx = c[0], cy = c[1], cz = c[2];

    int cnt = 0;
    for (int base = 0; base < NN && cnt < NSAMPLE; base += 64) {
        int j = base + lane;
        float dx = __fsub_rn(xb[j * 3 + 0], cx);
        float dy = __fsub_rn(xb[j * 3 + 1], cy);
        float dz = __fsub_rn(xb[j * 3 + 2], cz);
        float d2 = __fadd_rn(__fadd_rn(__fmul_rn(dx, dx), __fmul_rn(dy, dy)),
                             __fmul_rn(dz, dz));
        bool hit = d2 < RADIUS2;
        unsigned long long m = __ballot(hit);
        int pre = __popcll(m & ((1ull << lane) - 1ull));
        if (hit) {
            int pos = cnt + pre;
            if (pos < NSAMPLE) list[w][pos] = j;
        }
        cnt += __popcll(m);  // ballot result uniform -> cnt stays wave-uniform
    }
    __syncthreads();
    if (lane < NSAMPLE) {
        int first = list[w][0];  // >=1 hit always: centroid is a member point
        int v = (lane < cnt) ? list[w][lane] : first;
        nidx[(size_t)cid * NSAMPLE + lane] = v;
    }
}

// ---------------- grouped MLP + maxpool: one thread per (point,sample) ------
__global__ __launch_bounds__(256, 2) void mlp_kernel(
    const float* __restrict__ xyz, const float* __restrict__ features,
    const float* __restrict__ new_xyz, const int* __restrict__ nidx,
    const float* __restrict__ w1p, const float* __restrict__ b1,
    const float* __restrict__ w2, const float* __restrict__ b2,
    const float* __restrict__ w3, const float* __restrict__ b3,
    float* __restrict__ out) {
    const int gid = blockIdx.x * 256 + threadIdx.x;
    const int s = gid & 31;
    const int pg = gid >> 5;  // b*1024 + p
    const int b = pg >> 10;
    const int p = pg & 1023;

    const int idx = nidx[gid];
    const float* nc = new_xyz + (size_t)pg * 3;
    const float* pt = xyz + ((size_t)b * NN + idx) * 3;
    float gx = pt[0] - nc[0], gy = pt[1] - nc[1], gz = pt[2] - nc[2];

    float fin[64];
    const float4* fp = (const float4*)(features + ((size_t)b * NN + idx) * CC);
#pragma unroll
    for (int j = 0; j < 16; ++j) {
        float4 q = fp[j];
        fin[4 * j] = q.x; fin[4 * j + 1] = q.y;
        fin[4 * j + 2] = q.z; fin[4 * j + 3] = q.w;
    }

    float h1[64];
#pragma unroll
    for (int o = 0; o < 64; ++o) {
        const float4* wr = (const float4*)(w1p + o * 68);  // uniform -> s_load
        float acc = b1[o];
        float4 q0 = wr[0];
        acc = fmaf(q0.x, gx, acc);
        acc = fmaf(q0.y, gy, acc);
        acc = fmaf(q0.z, gz, acc);
        acc = fmaf(q0.w, fin[0], acc);
#pragma unroll
        for (int j = 1; j < 17; ++j) {
            float4 q = wr[j];
            int c0 = 4 * j - 3;
            acc = fmaf(q.x, fin[c0], acc);
            acc = fmaf(q.y, fin[c0 + 1], acc);
            acc = fmaf(q.z, fin[c0 + 2], acc);
            if (c0 + 3 < 64) acc = fmaf(q.w, fin[c0 + 3], acc);
        }
        h1[o] = fmaxf(acc, 0.0f);
    }

    float h2[64];
#pragma unroll
    for (int o = 0; o < 64; ++o) {
        const float4* wr = (const float4*)(w2 + o * 64);
        float acc = b2[o];
#pragma unroll
        for (int j = 0; j < 16; ++j) {
            float4 q = wr[j];
            acc = fmaf(q.x, h1[4 * j], acc);
            acc = fmaf(q.y, h1[4 * j + 1], acc);
            acc = fmaf(q.z, h1[4 * j + 2], acc);
            acc = fmaf(q.w, h1[4 * j + 3], acc);
        }
        h2[o] = fmaxf(acc, 0.0f);
    }

    float* ob = out + (size_t)b * 128 * NPOINT + p;
#pragma unroll
    for (int o = 0; o < 128; ++o) {
        const float4* wr = (const float4*)(w3 + o * 64);
        float acc = b3[o];
#pragma unroll
        for (int j = 0; j < 16; ++j) {
            float4 q = wr[j];
            acc = fmaf(q.x, h2[4 * j], acc);
            acc = fmaf(q.y, h2[4 * j + 1], acc);
            acc = fmaf(q.z, h2[4 * j + 2], acc);
            acc = fmaf(q.w, h2[4 * j + 3], acc);
        }
        float r = fmaxf(acc, 0.0f);
#pragma unroll
        for (int off = 1; off < 32; off <<= 1) {
            float orr = __shfl_xor(r, off);
            r = fmaxf(r, orr);
        }
        if (s == 0) ob[(size_t)o * NPOINT] = r;
    }
}

extern "C" void kernel_launch(void* const* d_in, const int* in_sizes, int n_in,
                              void* d_out, int out_size, void* d_ws, size_t ws_size,
                              hipStream_t stream) {
    const float* xyz = (const float*)d_in[0];
    const float* features = (const float*)d_in[1];
    const float* w1 = (const float*)d_in[2];
    const float* b1 = (const float*)d_in[3];
    const float* w2 = (const float*)d_in[4];
    const float* b2 = (const float*)d_in[5];
    const float* w3 = (const float*)d_in[6];
    const float* b3 = (const float*)d_in[7];

    float* out = (float*)d_out;
    float* new_xyz = out;                          // B*NPOINT*3
    float* new_feat = out + BB * NPOINT * 3;       // B*128*NPOINT

    int* nidx = (int*)d_ws;                        // B*NPOINT*NSAMPLE ints
    float* w1p = (float*)((char*)d_ws + (size_t)BB * NPOINT * NSAMPLE * sizeof(int));

    hipLaunchKernelGGL(repack_w1, dim3(1), dim3(256), 0, stream, w1, w1p);
    hipLaunchKernelGGL(fps_kernel, dim3(BB), dim3(FT), 0, stream, xyz, new_xyz);
    hipLaunchKernelGGL(ballquery_kernel, dim3(BB * NPOINT / 4), dim3(256), 0, stream,
                       xyz, new_xyz, nidx);
    hipLaunchKernelGGL(mlp_kernel, dim3(BB * NPOINT * NSAMPLE / 256), dim3(256), 0, stream,
                       xyz, features, new_xyz, nidx, w1p, b1, w2, b2, w3, b3, new_feat);
}

// Round 8
// 2196.997 us; speedup vs baseline: 1.1569x; 1.1569x over previous
//
#include <hip/hip_runtime.h>
#include <stdint.h>

#define BB 4
#define NN 16384
#define NPOINT 1024
#define NSAMPLE 32
#define CC 64
#define RADIUS2 0.00999999977648258209228515625f
#define BIGF 1.0e10f

#define FT 512     // fps threads per block (8 waves, 2/SIMD, 256-VGPR budget)
#define NPAIR 16   // point-pairs per thread (32 points/thread)

typedef float f32x2 __attribute__((ext_vector_type(2)));

// ---------------- repack w1 (64x67) -> (64x68) padded, pad=0 ----------------
__global__ __launch_bounds__(256) void repack_w1(const float* __restrict__ w1,
                                                 float* __restrict__ w1p) {
    int t = threadIdx.x;
    for (int i = t; i < 64 * 68; i += 256) {
        int o = i / 68, c = i % 68;
        w1p[i] = (c < 67) ? w1[o * 67 + c] : 0.0f;
    }
}

// DPP-based argmax step (max value, min index on ties) — validated bit-exact.
template <int CTRL>
__device__ __forceinline__ void amax_step(float& v, int& i) {
    int nv = __builtin_amdgcn_update_dpp(__float_as_int(v), __float_as_int(v),
                                         CTRL, 0xf, 0xf, false);
    int ni = __builtin_amdgcn_update_dpp(i, i, CTRL, 0xf, 0xf, false);
    float fv = __int_as_float(nv);
    if (fv > v || (fv == v && ni < i)) { v = fv; i = ni; }
}
__device__ __forceinline__ void wave_amax(float& v, int& i) {
    amax_step<0x111>(v, i);  // row_shr:1
    amax_step<0x112>(v, i);  // row_shr:2
    amax_step<0x114>(v, i);  // row_shr:4
    amax_step<0x118>(v, i);  // row_shr:8
    amax_step<0x142>(v, i);  // row_bcast:15
    amax_step<0x143>(v, i);  // row_bcast:31  -> lane63 holds full wave result
}

// ---------------- FPS: one 512-thread block per batch ----------------
// R0-R7 ledger: all variants 2.1-2.35us/iter. R4-vs-R7 A/B proved the kernel
// is ~94% active-CU VALU-issue-bound with ~590 wave-inst/wave/iter issued vs
// ~240 algorithmic -- bloat is NOT the distance math (pk-asm only -8%) but
// the per-iter LDS addressing at the 52-VGPR allocation, the cmp+2*cndmask
// per-element argmax tracking, and redundant 16-wave reduce work.
// R8 cuts the instruction count on every axis:
//  - 512 thr / launch_bounds(512,2) => 256-VGPR budget; px/py/pz/dd (128
//    VGPRs) register-resident via the ONE-TIME asm anchor that provably kept
//    pz resident in R4/R7. Loop has ZERO LDS reads / addressing.
//  - packed math via f32x2 C operators (compiler emits v_pk_add/mul_f32
//    without asm-constraint mov bloat).
//  - deferred argmax: running fmaxf (2/pair) instead of cmp+2*cndmask
//    (6/pair); first-occurrence index recovered by ONE descending equality
//    scan. Bit-exact: bv = exact max (associative, no NaN, all >= +0);
//    first slot equal to bv == strict-> ascending scan winner.
//  - 8-wave block: reduce tail is 6+3 DPP steps instead of 6+4.
// sx/sy stay in LDS ONLY for the winner lookup (z from global, as R7).
__global__ __launch_bounds__(FT, 2)
void fps_kernel(const float* xyz, float* new_xyz) {
    const int b = blockIdx.x;
    const int t = threadIdx.x;
    const int lane = t & 63;
    const int w = t >> 6;  // 0..7

    __shared__ float sx[NN];          // 64 KB (winner lookup only)
    __shared__ float sy[NN];          // 64 KB (winner lookup only)
    __shared__ float st[3 * NPOINT];  // 12 KB centroid stash
    __shared__ float2 svi[2][8];      // parity double-buffered (v, idx)

    const float* xb = xyz + (size_t)b * NN * 3;

    f32x2 px[NPAIR], py[NPAIR], pz[NPAIR], dd[NPAIR];

    // load + transpose: pair k covers points g = 2*(k*FT+t) and g+1
#pragma unroll
    for (int k = 0; k < NPAIR; ++k) {
        const float* p = xb + (size_t)6 * (k * FT + t);
        f32x2 a = *(const f32x2*)(p + 0);
        f32x2 bq = *(const f32x2*)(p + 2);
        f32x2 c = *(const f32x2*)(p + 4);
        int g = 2 * (k * FT + t);
        px[k].x = a.x;  py[k].x = a.y;  pz[k].x = bq.x;
        px[k].y = bq.y; py[k].y = c.x;  pz[k].y = c.y;
        *(f32x2*)&sx[g] = px[k];   // LDS copies for winner lookup
        *(f32x2*)&sy[g] = py[k];
        dd[k].x = BIGF; dd[k].y = BIGF;
    }
    // one-time remat blocker (R4/R7-proven): coords now defined by asm, not
    // by loads -> cannot be rematerialized; must stay in VGPRs (budget 256).
#pragma unroll
    for (int k = 0; k < NPAIR; ++k)
        asm("" : "+v"(px[k]), "+v"(py[k]), "+v"(pz[k]));

    // initial centroid = point 0
    float cx = xb[0], cy = xb[1], cz = xb[2];
    __syncthreads();

    for (int i = 0; i < NPOINT; ++i) {
        if (t == 0) {  // stash centroid in LDS; dumped to global after loop
            st[3 * i + 0] = cx; st[3 * i + 1] = cy; st[3 * i + 2] = cz;
        }
        if (i == NPOINT - 1) break;  // last centroid stashed; no next needed

        f32x2 c2x; c2x.x = cx; c2x.y = cx;
        f32x2 c2y; c2y.x = cy; c2y.y = cy;
        f32x2 c2z; c2z.x = cz; c2z.y = cz;

        // ---- packed distance update + running max (no index tracking) ----
        // EXACT numpy semantics per element: sub; products rounded
        // individually; sum order (x^2+y^2)+z^2; min.
        float mxx = -1.0f, mxy = -1.0f;
#pragma unroll
        for (int k = 0; k < NPAIR; ++k) {
            f32x2 dx = px[k] - c2x;       // v_pk_add_f32 (neg)
            f32x2 dy = py[k] - c2y;
            f32x2 dz = pz[k] - c2z;
            f32x2 m0 = dx * dx;           // v_pk_mul_f32
            f32x2 m1 = dy * dy;
            f32x2 m2 = dz * dz;
            f32x2 d  = (m0 + m1) + m2;    // v_pk_add_f32 x2
            dd[k].x = fminf(dd[k].x, d.x);
            dd[k].y = fminf(dd[k].y, d.y);
            mxx = fmaxf(mxx, dd[k].x);
            mxy = fmaxf(mxy, dd[k].y);
        }
        float bv = fmaxf(mxx, mxy);  // exact max of all 32 dd values

        // first-occurrence index: descending overwrite scan; .y before .x so
        // lower (k,e) wins. bv matches at least one slot by construction.
        int bj = 0;
#pragma unroll
        for (int k = NPAIR - 1; k >= 0; --k) {
            if (dd[k].y == bv) bj = 2 * k + 1;
            if (dd[k].x == bv) bj = 2 * k;
        }
        // global index: g = (bj>>1)*2*FT + 2*t + (bj&1); monotone in (k,e)
        // for fixed t -> in-thread first-occurrence holds
        int bi = (bj >> 1) * (2 * FT) + 2 * t + (bj & 1);

        wave_amax(bv, bi);
        if (lane == 63) svi[i & 1][w] = make_float2(bv, __int_as_float(bi));
        __syncthreads();

        // each lane reads ONE of the 8 wave slots; lanes 56..63 cover slots
        // 0..7, so 3 row_shr steps make lane63 the full block reduction.
        float2 s = svi[i & 1][lane & 7];
        float v2 = s.x;
        int i2 = __float_as_int(s.y);
        amax_step<0x111>(v2, i2);  // row_shr:1
        amax_step<0x112>(v2, i2);  // row_shr:2
        amax_step<0x114>(v2, i2);  // row_shr:4
        int ixs = __builtin_amdgcn_readlane(i2, 63);  // uniform -> SGPR

        // next centroid: x,y from LDS (exact copies), z via uniform global
        cx = sx[ixs];
        cy = sy[ixs];
        cz = xb[ixs * 3 + 2];
    }

    // dump stash -> global, coalesced (6 stores/thread)
    __syncthreads();
    float* ob = new_xyz + (size_t)b * NPOINT * 3;
    for (int j = t; j < 3 * NPOINT; j += FT) ob[j] = st[j];
}

// ---------------- ball query: one wave per centroid ----------------
__global__ __launch_bounds__(256) void ballquery_kernel(const float* __restrict__ xyz,
                                                        const float* __restrict__ new_xyz,
                                                        int* __restrict__ nidx) {
    const int t = threadIdx.x;
    const int lane = t & 63;
    const int w = t >> 6;
    const int cid = blockIdx.x * 4 + w;  // 0..4095
    const int b = cid >> 10;

    __shared__ int list[4][NSAMPLE];

    const float* xb = xyz + (size_t)b * NN * 3;
    const float* c = new_xyz + (size_t)cid * 3;
    float cx = c[0], cy = c[1], cz = c[2];

    int cnt = 0;
    for (int base = 0; base < NN && cnt < NSAMPLE; base += 64) {
        int j = base + lane;
        float dx = __fsub_rn(xb[j * 3 + 0], cx);
        float dy = __fsub_rn(xb[j * 3 + 1], cy);
        float dz = __fsub_rn(xb[j * 3 + 2], cz);
        float d2 = __fadd_rn(__fadd_rn(__fmul_rn(dx, dx), __fmul_rn(dy, dy)),
                             __fmul_rn(dz, dz));
        bool hit = d2 < RADIUS2;
        unsigned long long m = __ballot(hit);
        int pre = __popcll(m & ((1ull << lane) - 1ull));
        if (hit) {
            int pos = cnt + pre;
            if (pos < NSAMPLE) list[w][pos] = j;
        }
        cnt += __popcll(m);  // ballot result uniform -> cnt stays wave-uniform
    }
    __syncthreads();
    if (lane < NSAMPLE) {
        int first = list[w][0];  // >=1 hit always: centroid is a member point
        int v = (lane < cnt) ? list[w][lane] : first;
        nidx[(size_t)cid * NSAMPLE + lane] = v;
    }
}

// ---------------- grouped MLP + maxpool: one thread per (point,sample) ------
__global__ __launch_bounds__(256, 2) void mlp_kernel(
    const float* __restrict__ xyz, const float* __restrict__ features,
    const float* __restrict__ new_xyz, const int* __restrict__ nidx,
    const float* __restrict__ w1p, const float* __restrict__ b1,
    const float* __restrict__ w2, const float* __restrict__ b2,
    const float* __restrict__ w3, const float* __restrict__ b3,
    float* __restrict__ out) {
    const int gid = blockIdx.x * 256 + threadIdx.x;
    const int s = gid & 31;
    const int pg = gid >> 5;  // b*1024 + p
    const int b = pg >> 10;
    const int p = pg & 1023;

    const int idx = nidx[gid];
    const float* nc = new_xyz + (size_t)pg * 3;
    const float* pt = xyz + ((size_t)b * NN + idx) * 3;
    float gx = pt[0] - nc[0], gy = pt[1] - nc[1], gz = pt[2] - nc[2];

    float fin[64];
    const float4* fp = (const float4*)(features + ((size_t)b * NN + idx) * CC);
#pragma unroll
    for (int j = 0; j < 16; ++j) {
        float4 q = fp[j];
        fin[4 * j] = q.x; fin[4 * j + 1] = q.y;
        fin[4 * j + 2] = q.z; fin[4 * j + 3] = q.w;
    }

    float h1[64];
#pragma unroll
    for (int o = 0; o < 64; ++o) {
        const float4* wr = (const float4*)(w1p + o * 68);  // uniform -> s_load
        float acc = b1[o];
        float4 q0 = wr[0];
        acc = fmaf(q0.x, gx, acc);
        acc = fmaf(q0.y, gy, acc);
        acc = fmaf(q0.z, gz, acc);
        acc = fmaf(q0.w, fin[0], acc);
#pragma unroll
        for (int j = 1; j < 17; ++j) {
            float4 q = wr[j];
            int c0 = 4 * j - 3;
            acc = fmaf(q.x, fin[c0], acc);
            acc = fmaf(q.y, fin[c0 + 1], acc);
            acc = fmaf(q.z, fin[c0 + 2], acc);
            if (c0 + 3 < 64) acc = fmaf(q.w, fin[c0 + 3], acc);
        }
        h1[o] = fmaxf(acc, 0.0f);
    }

    float h2[64];
#pragma unroll
    for (int o = 0; o < 64; ++o) {
        const float4* wr = (const float4*)(w2 + o * 64);
        float acc = b2[o];
#pragma unroll
        for (int j = 0; j < 16; ++j) {
            float4 q = wr[j];
            acc = fmaf(q.x, h1[4 * j], acc);
            acc = fmaf(q.y, h1[4 * j + 1], acc);
            acc = fmaf(q.z, h1[4 * j + 2], acc);
            acc = fmaf(q.w, h1[4 * j + 3], acc);
        }
        h2[o] = fmaxf(acc, 0.0f);
    }

    float* ob = out + (size_t)b * 128 * NPOINT + p;
#pragma unroll
    for (int o = 0; o < 128; ++o) {
        const float4* wr = (const float4*)(w3 + o * 64);
        float acc = b3[o];
#pragma unroll
        for (int j = 0; j < 16; ++j) {
            float4 q = wr[j];
            acc = fmaf(q.x, h2[4 * j], acc);
            acc = fmaf(q.y, h2[4 * j + 1], acc);
            acc = fmaf(q.z, h2[4 * j + 2], acc);
            acc = fmaf(q.w, h2[4 * j + 3], acc);
        }
        float r = fmaxf(acc, 0.0f);
#pragma unroll
        for (int off = 1; off < 32; off <<= 1) {
            float orr = __shfl_xor(r, off);
            r = fmaxf(r, orr);
        }
        if (s == 0) ob[(size_t)o * NPOINT] = r;
    }
}

extern "C" void kernel_launch(void* const* d_in, const int* in_sizes, int n_in,
                              void* d_out, int out_size, void* d_ws, size_t ws_size,
                              hipStream_t stream) {
    const float* xyz = (const float*)d_in[0];
    const float* features = (const float*)d_in[1];
    const float* w1 = (const float*)d_in[2];
    const float* b1 = (const float*)d_in[3];
    const float* w2 = (const float*)d_in[4];
    const float* b2 = (const float*)d_in[5];
    const float* w3 = (const float*)d_in[6];
    const float* b3 = (const float*)d_in[7];

    float* out = (float*)d_out;
    float* new_xyz = out;                          // B*NPOINT*3
    float* new_feat = out + BB * NPOINT * 3;       // B*128*NPOINT

    int* nidx = (int*)d_ws;                        // B*NPOINT*NSAMPLE ints
    float* w1p = (float*)((char*)d_ws + (size_t)BB * NPOINT * NSAMPLE * sizeof(int));

    hipLaunchKernelGGL(repack_w1, dim3(1), dim3(256), 0, stream, w1, w1p);
    hipLaunchKernelGGL(fps_kernel, dim3(BB), dim3(FT), 0, stream, xyz, new_xyz);
    hipLaunchKernelGGL(ballquery_kernel, dim3(BB * NPOINT / 4), dim3(256), 0, stream,
                       xyz, new_xyz, nidx);
    hipLaunchKernelGGL(mlp_kernel, dim3(BB * NPOINT * NSAMPLE / 256), dim3(256), 0, stream,
                       xyz, features, new_xyz, nidx, w1p, b1, w2, b2, w3, b3, new_feat);
}

// Round 9
// 2175.920 us; speedup vs baseline: 1.1681x; 1.0097x over previous
//
#include <hip/hip_runtime.h>
#include <stdint.h>

#define BB 4
#define NN 16384
#define NPOINT 1024
#define NSAMPLE 32
#define CC 64
#define RADIUS2 0.00999999977648258209228515625f
#define BIGF 1.0e10f

#define FT 512     // fps threads per block (8 waves, 2/SIMD, 256-VGPR budget)
#define NPAIR 16   // point-pairs per thread (32 points/thread)

typedef float f32x2 __attribute__((ext_vector_type(2)));

// ---------------- repack w1 (64x67) -> (64x68) padded, pad=0 ----------------
__global__ __launch_bounds__(256) void repack_w1(const float* __restrict__ w1,
                                                 float* __restrict__ w1p) {
    int t = threadIdx.x;
    for (int i = t; i < 64 * 68; i += 256) {
        int o = i / 68, c = i % 68;
        w1p[i] = (c < 67) ? w1[o * 67 + c] : 0.0f;
    }
}

// DPP-based argmax step (max value, min index on ties) — validated bit-exact.
template <int CTRL>
__device__ __forceinline__ void amax_step(float& v, int& i) {
    int nv = __builtin_amdgcn_update_dpp(__float_as_int(v), __float_as_int(v),
                                         CTRL, 0xf, 0xf, false);
    int ni = __builtin_amdgcn_update_dpp(i, i, CTRL, 0xf, 0xf, false);
    float fv = __int_as_float(nv);
    if (fv > v || (fv == v && ni < i)) { v = fv; i = ni; }
}
__device__ __forceinline__ void wave_amax(float& v, int& i) {
    amax_step<0x111>(v, i);  // row_shr:1
    amax_step<0x112>(v, i);  // row_shr:2
    amax_step<0x114>(v, i);  // row_shr:4
    amax_step<0x118>(v, i);  // row_shr:8
    amax_step<0x142>(v, i);  // row_bcast:15
    amax_step<0x143>(v, i);  // row_bcast:31  -> lane63 holds full wave result
}

// ---------------- FPS: one 512-thread block per batch ----------------
// R8 (this structure, non-volatile anchor) broke the 2.2us plateau: 1.69us/
// iter. Post-mortem: VGPR=88 (<128 needed) and VALU-busy 1.12us/iter = ~670
// inst/wave vs ~330 static => coords still not fully register-resident. The
// non-volatile one-time anchor can be sunk/duplicated, and since sx[g]
// provably equals the stored px[k], LLVM may legally RELOAD coords from LDS
// and redo the AoS->SoA repack (6 v_mov/pair) + addressing = the residual
// bloat and the lgkmcnt stalls.
// R9: (1) asm VOLATILE one-time anchor (cannot be duplicated/sunk; "+v"
// output means post-anchor values may differ from the LDS copies -> LDS
// reload becomes ILLEGAL). (2) running max via nested fmaxf -> v_max3_f32
// (exact, bit-identical; halves the max chain). (3) dd anchored too.
// Everything else identical to the validated R8.
__global__ __launch_bounds__(FT, 2)
void fps_kernel(const float* xyz, float* new_xyz) {
    const int b = blockIdx.x;
    const int t = threadIdx.x;
    const int lane = t & 63;
    const int w = t >> 6;  // 0..7

    __shared__ float sx[NN];          // 64 KB (winner lookup only)
    __shared__ float sy[NN];          // 64 KB (winner lookup only)
    __shared__ float st[3 * NPOINT];  // 12 KB centroid stash
    __shared__ float2 svi[2][8];      // parity double-buffered (v, idx)

    const float* xb = xyz + (size_t)b * NN * 3;

    f32x2 px[NPAIR], py[NPAIR], pz[NPAIR], dd[NPAIR];

    // load + transpose: pair k covers points g = 2*(k*FT+t) and g+1
#pragma unroll
    for (int k = 0; k < NPAIR; ++k) {
        const float* p = xb + (size_t)6 * (k * FT + t);
        f32x2 a = *(const f32x2*)(p + 0);
        f32x2 bq = *(const f32x2*)(p + 2);
        f32x2 c = *(const f32x2*)(p + 4);
        int g = 2 * (k * FT + t);
        px[k].x = a.x;  py[k].x = a.y;  pz[k].x = bq.x;
        px[k].y = bq.y; py[k].y = c.x;  pz[k].y = c.y;
        *(f32x2*)&sx[g] = px[k];   // LDS copies for winner lookup
        *(f32x2*)&sy[g] = py[k];
        dd[k].x = BIGF; dd[k].y = BIGF;
    }
    // ONE-TIME VOLATILE anchor: cannot be sunk/duplicated; declares the
    // values (possibly) modified -> compiler may NOT substitute the LDS
    // copies for the registers. Coords + dd are pinned in VGPRs (budget 256).
#pragma unroll
    for (int k = 0; k < NPAIR; ++k)
        asm volatile("" : "+v"(px[k]), "+v"(py[k]), "+v"(pz[k]), "+v"(dd[k]));

    // initial centroid = point 0
    float cx = xb[0], cy = xb[1], cz = xb[2];
    __syncthreads();

    for (int i = 0; i < NPOINT; ++i) {
        if (t == 0) {  // stash centroid in LDS; dumped to global after loop
            st[3 * i + 0] = cx; st[3 * i + 1] = cy; st[3 * i + 2] = cz;
        }
        if (i == NPOINT - 1) break;  // last centroid stashed; no next needed

        f32x2 c2x; c2x.x = cx; c2x.y = cx;
        f32x2 c2y; c2y.x = cy; c2y.y = cy;
        f32x2 c2z; c2z.x = cz; c2z.y = cz;

        // ---- packed distance update + running max (no index tracking) ----
        // EXACT numpy semantics per element: sub; products rounded
        // individually; sum order (x^2+y^2)+z^2; min. Max is exact (no
        // rounding) -> nesting/fusion to v_max3 is bit-identical.
        float bv = -1.0f;
#pragma unroll
        for (int k = 0; k < NPAIR; ++k) {
            f32x2 dx = px[k] - c2x;       // v_pk_add_f32 (neg)
            f32x2 dy = py[k] - c2y;
            f32x2 dz = pz[k] - c2z;
            f32x2 m0 = dx * dx;           // v_pk_mul_f32
            f32x2 m1 = dy * dy;
            f32x2 m2 = dz * dz;
            f32x2 d  = (m0 + m1) + m2;    // v_pk_add_f32 x2
            dd[k].x = fminf(dd[k].x, d.x);
            dd[k].y = fminf(dd[k].y, d.y);
            bv = fmaxf(fmaxf(bv, dd[k].x), dd[k].y);  // -> v_max3_f32
        }

        // first-occurrence index: descending overwrite scan; .y before .x so
        // lower (k,e) wins. bv matches at least one slot by construction.
        int bj = 0;
#pragma unroll
        for (int k = NPAIR - 1; k >= 0; --k) {
            if (dd[k].y == bv) bj = 2 * k + 1;
            if (dd[k].x == bv) bj = 2 * k;
        }
        // global index: g = (bj>>1)*2*FT + 2*t + (bj&1); monotone in (k,e)
        // for fixed t -> in-thread first-occurrence holds
        int bi = (bj >> 1) * (2 * FT) + 2 * t + (bj & 1);

        wave_amax(bv, bi);
        if (lane == 63) svi[i & 1][w] = make_float2(bv, __int_as_float(bi));
        __syncthreads();

        // each lane reads ONE of the 8 wave slots; lanes 56..63 cover slots
        // 0..7, so 3 row_shr steps make lane63 the full block reduction.
        float2 s = svi[i & 1][lane & 7];
        float v2 = s.x;
        int i2 = __float_as_int(s.y);
        amax_step<0x111>(v2, i2);  // row_shr:1
        amax_step<0x112>(v2, i2);  // row_shr:2
        amax_step<0x114>(v2, i2);  // row_shr:4
        int ixs = __builtin_amdgcn_readlane(i2, 63);  // uniform -> SGPR

        // next centroid: x,y from LDS (exact copies), z via uniform global
        cx = sx[ixs];
        cy = sy[ixs];
        cz = xb[ixs * 3 + 2];
    }

    // dump stash -> global, coalesced (6 stores/thread)
    __syncthreads();
    float* ob = new_xyz + (size_t)b * NPOINT * 3;
    for (int j = t; j < 3 * NPOINT; j += FT) ob[j] = st[j];
}

// ---------------- ball query: one wave per centroid ----------------
__global__ __launch_bounds__(256) void ballquery_kernel(const float* __restrict__ xyz,
                                                        const float* __restrict__ new_xyz,
                                                        int* __restrict__ nidx) {
    const int t = threadIdx.x;
    const int lane = t & 63;
    const int w = t >> 6;
    const int cid = blockIdx.x * 4 + w;  // 0..4095
    const int b = cid >> 10;

    __shared__ int list[4][NSAMPLE];

    const float* xb = xyz + (size_t)b * NN * 3;
    const float* c = new_xyz + (size_t)cid * 3;
    float cx = c[0], cy = c[1], cz = c[2];

    int cnt = 0;
    for (int base = 0; base < NN && cnt < NSAMPLE; base += 64) {
        int j = base + lane;
        float dx = __fsub_rn(xb[j * 3 + 0], cx);
        float dy = __fsub_rn(xb[j * 3 + 1], cy);
        float dz = __fsub_rn(xb[j * 3 + 2], cz);
        float d2 = __fadd_rn(__fadd_rn(__fmul_rn(dx, dx), __fmul_rn(dy, dy)),
                             __fmul_rn(dz, dz));
        bool hit = d2 < RADIUS2;
        unsigned long long m = __ballot(hit);
        int pre = __popcll(m & ((1ull << lane) - 1ull));
        if (hit) {
            int pos = cnt + pre;
            if (pos < NSAMPLE) list[w][pos] = j;
        }
        cnt += __popcll(m);  // ballot result uniform -> cnt stays wave-uniform
    }
    __syncthreads();
    if (lane < NSAMPLE) {
        int first = list[w][0];  // >=1 hit always: centroid is a member point
        int v = (lane < cnt) ? list[w][lane] : first;
        nidx[(size_t)cid * NSAMPLE + lane] = v;
    }
}

// ---------------- grouped MLP + maxpool: one thread per (point,sample) ------
__global__ __launch_bounds__(256, 2) void mlp_kernel(
    const float* __restrict__ xyz, const float* __restrict__ features,
    const float* __restrict__ new_xyz, const int* __restrict__ nidx,
    const float* __restrict__ w1p, const float* __restrict__ b1,
    const float* __restrict__ w2, const float* __restrict__ b2,
    const float* __restrict__ w3, const float* __restrict__ b3,
    float* __restrict__ out) {
    const int gid = blockIdx.x * 256 + threadIdx.x;
    const int s = gid & 31;
    const int pg = gid >> 5;  // b*1024 + p
    const int b = pg >> 10;
    const int p = pg & 1023;

    const int idx = nidx[gid];
    const float* nc = new_xyz + (size_t)pg * 3;
    const float* pt = xyz + ((size_t)b * NN + idx) * 3;
    float gx = pt[0] - nc[0], gy = pt[1] - nc[1], gz = pt[2] - nc[2];

    float fin[64];
    const float4* fp = (const float4*)(features + ((size_t)b * NN + idx) * CC);
#pragma unroll
    for (int j = 0; j < 16; ++j) {
        float4 q = fp[j];
        fin[4 * j] = q.x; fin[4 * j + 1] = q.y;
        fin[4 * j + 2] = q.z; fin[4 * j + 3] = q.w;
    }

    float h1[64];
#pragma unroll
    for (int o = 0; o < 64; ++o) {
        const float4* wr = (const float4*)(w1p + o * 68);  // uniform -> s_load
        float acc = b1[o];
        float4 q0 = wr[0];
        acc = fmaf(q0.x, gx, acc);
        acc = fmaf(q0.y, gy, acc);
        acc = fmaf(q0.z, gz, acc);
        acc = fmaf(q0.w, fin[0], acc);
#pragma unroll
        for (int j = 1; j < 17; ++j) {
            float4 q = wr[j];
            int c0 = 4 * j - 3;
            acc = fmaf(q.x, fin[c0], acc);
            acc = fmaf(q.y, fin[c0 + 1], acc);
            acc = fmaf(q.z, fin[c0 + 2], acc);
            if (c0 + 3 < 64) acc = fmaf(q.w, fin[c0 + 3], acc);
        }
        h1[o] = fmaxf(acc, 0.0f);
    }

    float h2[64];
#pragma unroll
    for (int o = 0; o < 64; ++o) {
        const float4* wr = (const float4*)(w2 + o * 64);
        float acc = b2[o];
#pragma unroll
        for (int j = 0; j < 16; ++j) {
            float4 q = wr[j];
            acc = fmaf(q.x, h1[4 * j], acc);
            acc = fmaf(q.y, h1[4 * j + 1], acc);
            acc = fmaf(q.z, h1[4 * j + 2], acc);
            acc = fmaf(q.w, h1[4 * j + 3], acc);
        }
        h2[o] = fmaxf(acc, 0.0f);
    }

    float* ob = out + (size_t)b * 128 * NPOINT + p;
#pragma unroll
    for (int o = 0; o < 128; ++o) {
        const float4* wr = (const float4*)(w3 + o * 64);
        float acc = b3[o];
#pragma unroll
        for (int j = 0; j < 16; ++j) {
            float4 q = wr[j];
            acc = fmaf(q.x, h2[4 * j], acc);
            acc = fmaf(q.y, h2[4 * j + 1], acc);
            acc = fmaf(q.z, h2[4 * j + 2], acc);
            acc = fmaf(q.w, h2[4 * j + 3], acc);
        }
        float r = fmaxf(acc, 0.0f);
#pragma unroll
        for (int off = 1; off < 32; off <<= 1) {
            float orr = __shfl_xor(r, off);
            r = fmaxf(r, orr);
        }
        if (s == 0) ob[(size_t)o * NPOINT] = r;
    }
}

extern "C" void kernel_launch(void* const* d_in, const int* in_sizes, int n_in,
                              void* d_out, int out_size, void* d_ws, size_t ws_size,
                              hipStream_t stream) {
    const float* xyz = (const float*)d_in[0];
    const float* features = (const float*)d_in[1];
    const float* w1 = (const float*)d_in[2];
    const float* b1 = (const float*)d_in[3];
    const float* w2 = (const float*)d_in[4];
    const float* b2 = (const float*)d_in[5];
    const float* w3 = (const float*)d_in[6];
    const float* b3 = (const float*)d_in[7];

    float* out = (float*)d_out;
    float* new_xyz = out;                          // B*NPOINT*3
    float* new_feat = out + BB * NPOINT * 3;       // B*128*NPOINT

    int* nidx = (int*)d_ws;                        // B*NPOINT*NSAMPLE ints
    float* w1p = (float*)((char*)d_ws + (size_t)BB * NPOINT * NSAMPLE * sizeof(int));

    hipLaunchKernelGGL(repack_w1, dim3(1), dim3(256), 0, stream, w1, w1p);
    hipLaunchKernelGGL(fps_kernel, dim3(BB), dim3(FT), 0, stream, xyz, new_xyz);
    hipLaunchKernelGGL(ballquery_kernel, dim3(BB * NPOINT / 4), dim3(256), 0, stream,
                       xyz, new_xyz, nidx);
    hipLaunchKernelGGL(mlp_kernel, dim3(BB * NPOINT * NSAMPLE / 256), dim3(256), 0, stream,
                       xyz, features, new_xyz, nidx, w1p, b1, w2, b2, w3, b3, new_feat);
}

// Round 10
// 2174.728 us; speedup vs baseline: 1.1688x; 1.0005x over previous
//
#include <hip/hip_runtime.h>
#include <stdint.h>

#define BB 4
#define NN 16384
#define NPOINT 1024
#define NSAMPLE 32
#define CC 64
#define RADIUS2 0.00999999977648258209228515625f
#define BIGF 1.0e10f

#define FT 512     // fps threads per block (8 waves, 2/SIMD, 256-VGPR budget)
#define NPAIR 16   // point-pairs per thread (32 points/thread)

typedef float f32x2 __attribute__((ext_vector_type(2)));

// ---------------- repack w1 (64x67) -> (64x68) padded, pad=0 ----------------
__global__ __launch_bounds__(256) void repack_w1(const float* __restrict__ w1,
                                                 float* __restrict__ w1p) {
    int t = threadIdx.x;
    for (int i = t; i < 64 * 68; i += 256) {
        int o = i / 68, c = i % 68;
        w1p[i] = (c < 67) ? w1[o * 67 + c] : 0.0f;
    }
}

// DPP-based argmax step (max value, min index on ties) — validated bit-exact.
template <int CTRL>
__device__ __forceinline__ void amax_step(float& v, int& i) {
    int nv = __builtin_amdgcn_update_dpp(__float_as_int(v), __float_as_int(v),
                                         CTRL, 0xf, 0xf, false);
    int ni = __builtin_amdgcn_update_dpp(i, i, CTRL, 0xf, 0xf, false);
    float fv = __int_as_float(nv);
    if (fv > v || (fv == v && ni < i)) { v = fv; i = ni; }
}
__device__ __forceinline__ void wave_amax(float& v, int& i) {
    amax_step<0x111>(v, i);  // row_shr:1
    amax_step<0x112>(v, i);  // row_shr:2
    amax_step<0x114>(v, i);  // row_shr:4
    amax_step<0x118>(v, i);  // row_shr:8
    amax_step<0x142>(v, i);  // row_bcast:15
    amax_step<0x143>(v, i);  // row_bcast:31  -> lane63 holds full wave result
}

// ---------------- FPS: one 512-thread block per batch ----------------
// Ledger: R8 broke the 2.2us plateau (1.69us/iter); R7/R9 falsified the
// "VALU inst bloat" theory (scalar==pk, max3+volatile-anchor == nothing,
// VGPR stuck at 88 < the 128 the state needs). Revised diagnosis: the
// allocator live-range-SPLITS the anchored values -- spills them to scratch
// after the one-time anchor and reloads each iteration (~196KB/iter of
// L2-resident scratch traffic: invisible in FETCH_SIZE (HBM-only) and in
// VALUBusy (buffer_loads aren't VALU) -- matching the ~0.6us/iter stall).
// R10: per-ITERATION non-volatile anchors on ALL FOUR arrays at the loop
// top. A cross-iteration spill now forces a useless reload before every
// anchor, which the allocator won't do: 128 pinned + ~40 temps fits the
// 256-VGPR budget with slack. Non-volatile => no scheduling fence (R2's
// mistake was volatile + partial pinning + a 128 budget). Also: sx/sy LDS
// planes DROPPED -- winner coords come from one uniform 12B global read
// (identical exact values, same latency class); LDS shrinks to ~12.5KB.
__global__ __launch_bounds__(FT, 2)
void fps_kernel(const float* xyz, float* new_xyz) {
    const int b = blockIdx.x;
    const int t = threadIdx.x;
    const int lane = t & 63;
    const int w = t >> 6;  // 0..7

    __shared__ float st[3 * NPOINT];  // 12 KB centroid stash
    __shared__ float2 svi[2][8];      // parity double-buffered (v, idx)

    const float* xb = xyz + (size_t)b * NN * 3;

    f32x2 px[NPAIR], py[NPAIR], pz[NPAIR], dd[NPAIR];

    // load + transpose: pair k covers points g = 2*(k*FT+t) and g+1
#pragma unroll
    for (int k = 0; k < NPAIR; ++k) {
        const float* p = xb + (size_t)6 * (k * FT + t);
        f32x2 a = *(const f32x2*)(p + 0);
        f32x2 bq = *(const f32x2*)(p + 2);
        f32x2 c = *(const f32x2*)(p + 4);
        px[k].x = a.x;  py[k].x = a.y;  pz[k].x = bq.x;
        px[k].y = bq.y; py[k].y = c.x;  pz[k].y = c.y;
        dd[k].x = BIGF; dd[k].y = BIGF;
    }

    // initial centroid = point 0
    float cx = xb[0], cy = xb[1], cz = xb[2];

    for (int i = 0; i < NPOINT; ++i) {
        // Per-iteration register anchor (non-volatile: no scheduling fence).
        // Forces all 128 floats of loop state to be live VGPRs at the top of
        // EVERY iteration -> cross-iteration scratch spill becomes pure
        // waste, so the allocator keeps them resident (budget 256).
#pragma unroll
        for (int k = 0; k < NPAIR; ++k)
            asm("" : "+v"(px[k]), "+v"(py[k]), "+v"(pz[k]), "+v"(dd[k]));

        if (t == 0) {  // stash centroid in LDS; dumped to global after loop
            st[3 * i + 0] = cx; st[3 * i + 1] = cy; st[3 * i + 2] = cz;
        }
        if (i == NPOINT - 1) break;  // last centroid stashed; no next needed

        f32x2 c2x; c2x.x = cx; c2x.y = cx;
        f32x2 c2y; c2y.x = cy; c2y.y = cy;
        f32x2 c2z; c2z.x = cz; c2z.y = cz;

        // ---- packed distance update + running max (no index tracking) ----
        // EXACT numpy semantics per element: sub; products rounded
        // individually; sum order (x^2+y^2)+z^2; min. Max is exact (no
        // rounding) -> nesting/fusion to v_max3 is bit-identical.
        float bv = -1.0f;
#pragma unroll
        for (int k = 0; k < NPAIR; ++k) {
            f32x2 dx = px[k] - c2x;       // v_pk_add_f32 (neg)
            f32x2 dy = py[k] - c2y;
            f32x2 dz = pz[k] - c2z;
            f32x2 m0 = dx * dx;           // v_pk_mul_f32
            f32x2 m1 = dy * dy;
            f32x2 m2 = dz * dz;
            f32x2 d  = (m0 + m1) + m2;    // v_pk_add_f32 x2
            dd[k].x = fminf(dd[k].x, d.x);
            dd[k].y = fminf(dd[k].y, d.y);
            bv = fmaxf(fmaxf(bv, dd[k].x), dd[k].y);  // -> v_max3_f32
        }

        // first-occurrence index: descending overwrite scan; .y before .x so
        // lower (k,e) wins. bv matches at least one slot by construction.
        int bj = 0;
#pragma unroll
        for (int k = NPAIR - 1; k >= 0; --k) {
            if (dd[k].y == bv) bj = 2 * k + 1;
            if (dd[k].x == bv) bj = 2 * k;
        }
        // global index: g = (bj>>1)*2*FT + 2*t + (bj&1); monotone in (k,e)
        // for fixed t -> in-thread first-occurrence holds
        int bi = (bj >> 1) * (2 * FT) + 2 * t + (bj & 1);

        wave_amax(bv, bi);
        if (lane == 63) svi[i & 1][w] = make_float2(bv, __int_as_float(bi));
        __syncthreads();

        // each lane reads ONE of the 8 wave slots; lanes 56..63 cover slots
        // 0..7, so 3 row_shr steps make lane63 the full block reduction.
        float2 s = svi[i & 1][lane & 7];
        float v2 = s.x;
        int i2 = __float_as_int(s.y);
        amax_step<0x111>(v2, i2);  // row_shr:1
        amax_step<0x112>(v2, i2);  // row_shr:2
        amax_step<0x114>(v2, i2);  // row_shr:4
        int ixs = __builtin_amdgcn_readlane(i2, 63);  // uniform -> SGPR

        // next centroid: one uniform 12B global read (exact source values)
        cx = xb[ixs * 3 + 0];
        cy = xb[ixs * 3 + 1];
        cz = xb[ixs * 3 + 2];
    }

    // dump stash -> global, coalesced (6 stores/thread)
    __syncthreads();
    float* ob = new_xyz + (size_t)b * NPOINT * 3;
    for (int j = t; j < 3 * NPOINT; j += FT) ob[j] = st[j];
}

// ---------------- ball query: one wave per centroid ----------------
__global__ __launch_bounds__(256) void ballquery_kernel(const float* __restrict__ xyz,
                                                        const float* __restrict__ new_xyz,
                                                        int* __restrict__ nidx) {
    const int t = threadIdx.x;
    const int lane = t & 63;
    const int w = t >> 6;
    const int cid = blockIdx.x * 4 + w;  // 0..4095
    const int b = cid >> 10;

    __shared__ int list[4][NSAMPLE];

    const float* xb = xyz + (size_t)b * NN * 3;
    const float* c = new_xyz + (size_t)cid * 3;
    float cx = c[0], cy = c[1], cz = c[2];

    int cnt = 0;
    for (int base = 0; base < NN && cnt < NSAMPLE; base += 64) {
        int j = base + lane;
        float dx = __fsub_rn(xb[j * 3 + 0], cx);
        float dy = __fsub_rn(xb[j * 3 + 1], cy);
        float dz = __fsub_rn(xb[j * 3 + 2], cz);
        float d2 = __fadd_rn(__fadd_rn(__fmul_rn(dx, dx), __fmul_rn(dy, dy)),
                             __fmul_rn(dz, dz));
        bool hit = d2 < RADIUS2;
        unsigned long long m = __ballot(hit);
        int pre = __popcll(m & ((1ull << lane) - 1ull));
        if (hit) {
            int pos = cnt + pre;
            if (pos < NSAMPLE) list[w][pos] = j;
        }
        cnt += __popcll(m);  // ballot result uniform -> cnt stays wave-uniform
    }
    __syncthreads();
    if (lane < NSAMPLE) {
        int first = list[w][0];  // >=1 hit always: centroid is a member point
        int v = (lane < cnt) ? list[w][lane] : first;
        nidx[(size_t)cid * NSAMPLE + lane] = v;
    }
}

// ---------------- grouped MLP + maxpool: one thread per (point,sample) ------
__global__ __launch_bounds__(256, 2) void mlp_kernel(
    const float* __restrict__ xyz, const float* __restrict__ features,
    const float* __restrict__ new_xyz, const int* __restrict__ nidx,
    const float* __restrict__ w1p, const float* __restrict__ b1,
    const float* __restrict__ w2, const float* __restrict__ b2,
    const float* __restrict__ w3, const float* __restrict__ b3,
    float* __restrict__ out) {
    const int gid = blockIdx.x * 256 + threadIdx.x;
    const int s = gid & 31;
    const int pg = gid >> 5;  // b*1024 + p
    const int b = pg >> 10;
    const int p = pg & 1023;

    const int idx = nidx[gid];
    const float* nc = new_xyz + (size_t)pg * 3;
    const float* pt = xyz + ((size_t)b * NN + idx) * 3;
    float gx = pt[0] - nc[0], gy = pt[1] - nc[1], gz = pt[2] - nc[2];

    float fin[64];
    const float4* fp = (const float4*)(features + ((size_t)b * NN + idx) * CC);
#pragma unroll
    for (int j = 0; j < 16; ++j) {
        float4 q = fp[j];
        fin[4 * j] = q.x; fin[4 * j + 1] = q.y;
        fin[4 * j + 2] = q.z; fin[4 * j + 3] = q.w;
    }

    float h1[64];
#pragma unroll
    for (int o = 0; o < 64; ++o) {
        const float4* wr = (const float4*)(w1p + o * 68);  // uniform -> s_load
        float acc = b1[o];
        float4 q0 = wr[0];
        acc = fmaf(q0.x, gx, acc);
        acc = fmaf(q0.y, gy, acc);
        acc = fmaf(q0.z, gz, acc);
        acc = fmaf(q0.w, fin[0], acc);
#pragma unroll
        for (int j = 1; j < 17; ++j) {
            float4 q = wr[j];
            int c0 = 4 * j - 3;
            acc = fmaf(q.x, fin[c0], acc);
            acc = fmaf(q.y, fin[c0 + 1], acc);
            acc = fmaf(q.z, fin[c0 + 2], acc);
            if (c0 + 3 < 64) acc = fmaf(q.w, fin[c0 + 3], acc);
        }
        h1[o] = fmaxf(acc, 0.0f);
    }

    float h2[64];
#pragma unroll
    for (int o = 0; o < 64; ++o) {
        const float4* wr = (const float4*)(w2 + o * 64);
        float acc = b2[o];
#pragma unroll
        for (int j = 0; j < 16; ++j) {
            float4 q = wr[j];
            acc = fmaf(q.x, h1[4 * j], acc);
            acc = fmaf(q.y, h1[4 * j + 1], acc);
            acc = fmaf(q.z, h1[4 * j + 2], acc);
            acc = fmaf(q.w, h1[4 * j + 3], acc);
        }
        h2[o] = fmaxf(acc, 0.0f);
    }

    float* ob = out + (size_t)b * 128 * NPOINT + p;
#pragma unroll
    for (int o = 0; o < 128; ++o) {
        const float4* wr = (const float4*)(w3 + o * 64);
        float acc = b3[o];
#pragma unroll
        for (int j = 0; j < 16; ++j) {
            float4 q = wr[j];
            acc = fmaf(q.x, h2[4 * j], acc);
            acc = fmaf(q.y, h2[4 * j + 1], acc);
            acc = fmaf(q.z, h2[4 * j + 2], acc);
            acc = fmaf(q.w, h2[4 * j + 3], acc);
        }
        float r = fmaxf(acc, 0.0f);
#pragma unroll
        for (int off = 1; off < 32; off <<= 1) {
            float orr = __shfl_xor(r, off);
            r = fmaxf(r, orr);
        }
        if (s == 0) ob[(size_t)o * NPOINT] = r;
    }
}

extern "C" void kernel_launch(void* const* d_in, const int* in_sizes, int n_in,
                              void* d_out, int out_size, void* d_ws, size_t ws_size,
                              hipStream_t stream) {
    const float* xyz = (const float*)d_in[0];
    const float* features = (const float*)d_in[1];
    const float* w1 = (const float*)d_in[2];
    const float* b1 = (const float*)d_in[3];
    const float* w2 = (const float*)d_in[4];
    const float* b2 = (const float*)d_in[5];
    const float* w3 = (const float*)d_in[6];
    const float* b3 = (const float*)d_in[7];

    float* out = (float*)d_out;
    float* new_xyz = out;                          // B*NPOINT*3
    float* new_feat = out + BB * NPOINT * 3;       // B*128*NPOINT

    int* nidx = (int*)d_ws;                        // B*NPOINT*NSAMPLE ints
    float* w1p = (float*)((char*)d_ws + (size_t)BB * NPOINT * NSAMPLE * sizeof(int));

    hipLaunchKernelGGL(repack_w1, dim3(1), dim3(256), 0, stream, w1, w1p);
    hipLaunchKernelGGL(fps_kernel, dim3(BB), dim3(FT), 0, stream, xyz, new_xyz);
    hipLaunchKernelGGL(ballquery_kernel, dim3(BB * NPOINT / 4), dim3(256), 0, stream,
                       xyz, new_xyz, nidx);
    hipLaunchKernelGGL(mlp_kernel, dim3(BB * NPOINT * NSAMPLE / 256), dim3(256), 0, stream,
                       xyz, features, new_xyz, nidx, w1p, b1, w2, b2, w3, b3, new_feat);
}